// Round 4
// baseline (8890.208 us; speedup 1.0000x reference)
//
#include <hip/hip_runtime.h>

#define BATCH 65536
#define T 500
#define STRIDE 36   // words per sample region in act LDS (16B-aligned, R3-proven)

typedef __attribute__((ext_vector_type(8))) short bf16x8;
typedef __attribute__((ext_vector_type(4))) float f32x4;
typedef __attribute__((ext_vector_type(2))) unsigned u32x2;

#define MFMA(A, B, C) __builtin_amdgcn_mfma_f32_16x16x32_bf16(A, B, C, 0, 0, 0)
#define PSEL 0x07060302u   // v_perm: low16 = hi16(srcB), high16 = hi16(srcA)

union U4 { unsigned u[4]; bf16x8 v; };

__device__ __forceinline__ float fast_tanh(float x) {
    float e = __expf(2.0f * x);
    return 1.0f - 2.0f / (e + 1.0f);
}
__device__ __forceinline__ float fast_sp(float x) {
    float e = __expf(-fabsf(x));
    return fmaxf(x, 0.0f) + __logf(1.0f + e);
}

// truncation split: hi = trunc_bf16(x) (exact top-16), lo = trunc_bf16(x - hi).
// Split rounding error is absorbed by lo; dropped residual <= 2^-16 |x|.
__device__ __forceinline__ void tsplit(float x, short& hs, short& ls) {
    unsigned uh = __float_as_uint(x) & 0xFFFF0000u;
    float r = x - __uint_as_float(uh);
    hs = (short)(uh >> 16);
    ls = (short)(__float_as_uint(r) >> 16);
}

// ---- layer-1 merged A-fragment (k-packed hi/lo/bias, one MFMA per tile) ----
// k-slot table (A row = output feature, matched by the B y-fragment below):
//  k0..k7  (G=0): wa_h wb_h b_h wa_h wb_h wa_h wb_h wa_l
//  k8..k11 (G=1): wb_l wa_l wb_l b_l
__device__ __forceinline__ void build_l1(const float* __restrict__ W,
                                         const float* __restrict__ Bv,
                                         int Mreal, int t, int lane, bf16x8& A) {
    int row = t * 16 + (lane & 15);
    int G = lane >> 4;
    float wa = 0.f, wb = 0.f, bi = 0.f;
    if (row < Mreal) { wa = W[2 * row]; wb = W[2 * row + 1]; bi = Bv[row]; }
    short wah, wal, wbh, wbl, bih, bil;
    tsplit(wa, wah, wal);
    tsplit(wb, wbh, wbl);
    tsplit(bi, bih, bil);
    #pragma unroll
    for (int j = 0; j < 8; ++j) A[j] = 0;
    if (G == 0) {
        A[0] = wah; A[1] = wbh; A[2] = bih; A[3] = wah;
        A[4] = wbh; A[5] = wah; A[6] = wbh; A[7] = wal;
    } else if (G == 1) {
        A[0] = wbl; A[1] = wal; A[2] = wbl; A[3] = bil;
    }
}

// ---- layer-2 A-fragment (hi+lo), row-major W[M][K] ----
__device__ __forceinline__ void build_frag(const float* __restrict__ W,
                                           int Mreal, int Kreal, int Ks,
                                           int t, int u, int lane,
                                           bf16x8& hi, bf16x8& lo) {
    int row = t * 16 + (lane & 15);
    int kb = u * 32 + (lane >> 4) * 8;
    #pragma unroll
    for (int j = 0; j < 8; ++j) {
        int k = kb + j;
        float w = (row < Mreal && k < Kreal) ? W[row * Ks + k] : 0.0f;
        short hs, ls;
        tsplit(w, hs, ls);
        hi[j] = hs; lo[j] = ls;
    }
}

// tanh + trunc-split + LDS store (word w of sample region = features 2w,2w+1)
__device__ __forceinline__ void act_store_tanh(const f32x4* d,
                                               unsigned* ldsH, unsigned* ldsL,
                                               int cb, int G) {
    #pragma unroll
    for (int t = 0; t < 4; ++t) {
        float a0 = fast_tanh(d[t][0]);
        float a1 = fast_tanh(d[t][1]);
        float a2 = fast_tanh(d[t][2]);
        float a3 = fast_tanh(d[t][3]);
        unsigned u0 = __float_as_uint(a0), u1 = __float_as_uint(a1);
        unsigned u2 = __float_as_uint(a2), u3 = __float_as_uint(a3);
        unsigned h01 = __builtin_amdgcn_perm(u1, u0, PSEL);
        unsigned h23 = __builtin_amdgcn_perm(u3, u2, PSEL);
        float r0 = a0 - __uint_as_float(u0 & 0xFFFF0000u);
        float r1 = a1 - __uint_as_float(u1 & 0xFFFF0000u);
        float r2 = a2 - __uint_as_float(u2 & 0xFFFF0000u);
        float r3 = a3 - __uint_as_float(u3 & 0xFFFF0000u);
        unsigned l01 = __builtin_amdgcn_perm(__float_as_uint(r1), __float_as_uint(r0), PSEL);
        unsigned l23 = __builtin_amdgcn_perm(__float_as_uint(r3), __float_as_uint(r2), PSEL);
        int wo = cb + 8 * t + 2 * G;
        *reinterpret_cast<u32x2*>(&ldsH[wo]) = (u32x2){h01, h23};
        *reinterpret_cast<u32x2*>(&ldsL[wo]) = (u32x2){l01, l23};
    }
}

__global__ void __launch_bounds__(256, 2)
node_kernel(const float* __restrict__ y0,
            const float* __restrict__ tt,
            const float* __restrict__ fw1, const float* __restrict__ fb1,
            const float* __restrict__ fw2, const float* __restrict__ fb2,
            const float* __restrict__ fw3, const float* __restrict__ fb3,
            const float* __restrict__ gw1, const float* __restrict__ gb1,
            const float* __restrict__ gw2, const float* __restrict__ gb2,
            const float* __restrict__ gw3, const float* __restrict__ gb3,
            float* __restrict__ out)
{
    __shared__ __align__(16) unsigned lds_fhi[4][16 * STRIDE];
    __shared__ __align__(16) unsigned lds_flo[4][16 * STRIDE];
    __shared__ __align__(16) unsigned lds_ghi[4][16 * STRIDE];
    __shared__ __align__(16) unsigned lds_glo[4][16 * STRIDE];
    __shared__ float lds_y[4][2][16][2];
    __shared__ __align__(16) float lds_b2f[64];
    __shared__ __align__(16) float lds_b2g[64];
    __shared__ __align__(16) float lds_w3[4][64];   // f0,f1,g0,g1 rows (g padded)

    const int lane  = threadIdx.x & 63;
    const int wIdx  = threadIdx.x >> 6;
    const int waveG = blockIdx.x * 4 + wIdx;
    const int c     = lane & 15;
    const int G     = lane >> 4;
    const bool lo16 = (lane < 16);
    const int cb    = c * STRIDE;

    // block-shared tables
    if (threadIdx.x < 64) {
        int i = threadIdx.x;
        lds_b2f[i] = fb2[i];
        lds_b2g[i] = (i < 52) ? gb2[i] : 0.0f;
        lds_w3[0][i] = fw3[i];
        lds_w3[1][i] = fw3[64 + i];
        lds_w3[2][i] = (i < 52) ? gw3[i] : 0.0f;
        lds_w3[3][i] = (i < 52) ? gw3[52 + i] : 0.0f;
    }
    __syncthreads();

    const float dt = tt[1] - tt[0];
    const float b3a = fb3[0] + gb3[0];
    const float b3b = fb3[1] + gb3[1];

    // ---- persistent weight fragments ----
    bf16x8 fA1[4], gA1[4];
    bf16x8 fw2h[4][2], fw2l[4][2], gw2h[4][2], gw2l[4][2];
    #pragma unroll
    for (int t = 0; t < 4; ++t) {
        build_l1(fw1, fb1, 64, t, lane, fA1[t]);
        build_l1(gw1, gb1, 52, t, lane, gA1[t]);
        #pragma unroll
        for (int u = 0; u < 2; ++u) {
            build_frag(fw2, 64, 64, 64, t, u, lane, fw2h[t][u], fw2l[t][u]);
            build_frag(gw2, 52, 52, 52, t, u, lane, gw2h[t][u], gw2l[t][u]);
        }
    }
    const f32x4 zero4 = {0.f, 0.f, 0.f, 0.f};

    // ---- y0 init ----
    #pragma unroll 1
    for (int ct = 0; ct < 2; ++ct) {
        int sample = waveG * 32 + ct * 16 + c;
        if (lo16) {
            float2 yv = reinterpret_cast<const float2*>(y0)[sample];
            lds_y[wIdx][ct][c][0] = yv.x;
            lds_y[wIdx][ct][c][1] = yv.y;
            reinterpret_cast<float2*>(out)[sample] = yv;
        }
    }

    // ---- time loop ----
    #pragma unroll 1
    for (int s = 1; s < T; ++s) {
        #pragma unroll 1
        for (int ct = 0; ct < 2; ++ct) {
            float ya = lds_y[wIdx][ct][c][0];
            float yb = lds_y[wIdx][ct][c][1];

            // ---- y trunc 3-split -> k-packed B fragment ----
            unsigned ua = __float_as_uint(ya), ub = __float_as_uint(yb);
            unsigned uah = ua & 0xFFFF0000u;
            float ra = ya - __uint_as_float(uah);
            unsigned uam = __float_as_uint(ra) & 0xFFFF0000u;
            float ra2 = ra - __uint_as_float(uam);
            unsigned ubh = ub & 0xFFFF0000u;
            float rb = yb - __uint_as_float(ubh);
            unsigned ubm = __float_as_uint(rb) & 0xFFFF0000u;
            float rb2 = rb - __uint_as_float(ubm);

            unsigned w0g0 = __builtin_amdgcn_perm(ub, ua, PSEL);                    // yaH|ybH
            unsigned w1g0 = 0x00003F80u | uam;                                      // 1.0|yaM
            unsigned w2g0 = __builtin_amdgcn_perm(__float_as_uint(ra2), __float_as_uint(rb), PSEL); // ybM|yaL
            unsigned w3g0 = __builtin_amdgcn_perm(ua, __float_as_uint(rb2), PSEL);  // ybL|yaH
            unsigned w0g1 = __builtin_amdgcn_perm(__float_as_uint(ra), ub, PSEL);   // ybH|yaM
            unsigned w1g1 = (ubm >> 16) | 0x3F800000u;                              // ybM|1.0

            U4 yB;
            yB.u[0] = (G == 0) ? w0g0 : ((G == 1) ? w0g1 : 0u);
            yB.u[1] = (G == 0) ? w1g0 : ((G == 1) ? w1g1 : 0u);
            yB.u[2] = (G == 0) ? w2g0 : 0u;
            yB.u[3] = (G == 0) ? w3g0 : 0u;

            // ---- layer 1: one MFMA per tile ----
            f32x4 d1f[4], d1g[4];
            #pragma unroll
            for (int t = 0; t < 4; ++t) d1f[t] = MFMA(fA1[t], yB.v, zero4);
            act_store_tanh(d1f, lds_fhi[wIdx], lds_flo[wIdx], cb, G);
            #pragma unroll
            for (int t = 0; t < 4; ++t) d1g[t] = MFMA(gA1[t], yB.v, zero4);
            act_store_tanh(d1g, lds_ghi[wIdx], lds_glo[wIdx], cb, G);

            // ---- layer 2: 3 split passes, bias C-init from LDS ----
            bf16x8 hH[2], hL[2];
            #pragma unroll
            for (int u = 0; u < 2; ++u) {
                int ro = cb + 16 * u + 4 * G;
                hH[u] = *reinterpret_cast<const bf16x8*>(&lds_fhi[wIdx][ro]);
                hL[u] = *reinterpret_cast<const bf16x8*>(&lds_flo[wIdx][ro]);
            }
            f32x4 d2f[4], d2g[4];
            #pragma unroll
            for (int t = 0; t < 4; ++t) {
                f32x4 a = *reinterpret_cast<const f32x4*>(&lds_b2f[16 * t + 4 * G]);
                #pragma unroll
                for (int u = 0; u < 2; ++u) {
                    a = MFMA(fw2h[t][u], hH[u], a);
                    a = MFMA(fw2h[t][u], hL[u], a);
                    a = MFMA(fw2l[t][u], hH[u], a);
                }
                d2f[t] = a;
            }
            #pragma unroll
            for (int u = 0; u < 2; ++u) {
                int ro = cb + 16 * u + 4 * G;
                hH[u] = *reinterpret_cast<const bf16x8*>(&lds_ghi[wIdx][ro]);
                hL[u] = *reinterpret_cast<const bf16x8*>(&lds_glo[wIdx][ro]);
            }
            #pragma unroll
            for (int t = 0; t < 4; ++t) {
                f32x4 a = *reinterpret_cast<const f32x4*>(&lds_b2g[16 * t + 4 * G]);
                #pragma unroll
                for (int u = 0; u < 2; ++u) {
                    a = MFMA(gw2h[t][u], hH[u], a);
                    a = MFMA(gw2h[t][u], hL[u], a);
                    a = MFMA(gw2l[t][u], hH[u], a);
                }
                d2g[t] = a;
            }

            // ---- layer 3 on VALU: softplus + f32 dots + butterfly reduce ----
            float pa = 0.f, pb = 0.f;
            #pragma unroll
            for (int t = 0; t < 4; ++t) {
                int fo = 16 * t + 4 * G;
                f32x4 wf0 = *reinterpret_cast<const f32x4*>(&lds_w3[0][fo]);
                f32x4 wf1 = *reinterpret_cast<const f32x4*>(&lds_w3[1][fo]);
                #pragma unroll
                for (int r = 0; r < 4; ++r) {
                    float sv = fast_sp(d2f[t][r]);
                    pa = fmaf(wf0[r], sv, pa);
                    pb = fmaf(wf1[r], sv, pb);
                }
                f32x4 wg0 = *reinterpret_cast<const f32x4*>(&lds_w3[2][fo]);
                f32x4 wg1 = *reinterpret_cast<const f32x4*>(&lds_w3[3][fo]);
                #pragma unroll
                for (int r = 0; r < 4; ++r) {
                    float sv = fast_sp(d2g[t][r]);
                    pa = fmaf(wg0[r], sv, pa);
                    pb = fmaf(wg1[r], sv, pb);
                }
            }
            pa += __shfl_xor(pa, 16); pa += __shfl_xor(pa, 32);
            pb += __shfl_xor(pb, 16); pb += __shfl_xor(pb, 32);

            // ---- Euler update + store ----
            if (lo16) {
                float nya = fmaf(pa + b3a, dt, ya);
                float nyb = fmaf(pb + b3b, dt, yb);
                lds_y[wIdx][ct][c][0] = nya;
                lds_y[wIdx][ct][c][1] = nyb;
                int sample = waveG * 32 + ct * 16 + c;
                reinterpret_cast<float2*>(out)[(size_t)s * BATCH + sample] =
                    make_float2(nya, nyb);
            }
        }
    }
}

extern "C" void kernel_launch(void* const* d_in, const int* in_sizes, int n_in,
                              void* d_out, int out_size, void* d_ws, size_t ws_size,
                              hipStream_t stream) {
    const float* y0  = (const float*)d_in[0];
    const float* tt  = (const float*)d_in[1];
    const float* fw1 = (const float*)d_in[2];
    const float* fb1 = (const float*)d_in[3];
    const float* fw2 = (const float*)d_in[4];
    const float* fb2 = (const float*)d_in[5];
    const float* fw3 = (const float*)d_in[6];
    const float* fb3 = (const float*)d_in[7];
    const float* gw1 = (const float*)d_in[8];
    const float* gb1 = (const float*)d_in[9];
    const float* gw2 = (const float*)d_in[10];
    const float* gb2 = (const float*)d_in[11];
    const float* gw3 = (const float*)d_in[12];
    const float* gb3 = (const float*)d_in[13];
    float* out = (float*)d_out;

    dim3 grid(512);    // 2048 waves, 32 samples/wave -> 2 blocks/CU
    dim3 block(256);
    hipLaunchKernelGGL(node_kernel, grid, block, 0, stream,
                       y0, tt, fw1, fb1, fw2, fb2, fw3, fb3,
                       gw1, gb1, gw2, gb2, gw3, gb3, out);
}

// Round 5
// 8494.437 us; speedup vs baseline: 1.0466x; 1.0466x over previous
//
#include <hip/hip_runtime.h>

#define BATCH 65536
#define T 500
#define STRIDE 36   // words per sample region in act LDS (16B-aligned, R3-proven)

typedef __attribute__((ext_vector_type(8))) short bf16x8;
typedef __attribute__((ext_vector_type(4))) float f32x4;
typedef __attribute__((ext_vector_type(2))) unsigned u32x2;

#define MFMA(A, B, C) __builtin_amdgcn_mfma_f32_16x16x32_bf16(A, B, C, 0, 0, 0)
#define PSEL 0x07060302u   // v_perm: low16 = hi16(srcB), high16 = hi16(srcA)

union U4 { unsigned u[4]; bf16x8 v; };

__device__ __forceinline__ float fast_tanh(float x) {
    float e = __expf(2.0f * x);
    return 1.0f - 2.0f / (e + 1.0f);
}
__device__ __forceinline__ float fast_sp(float x) {
    float e = __expf(-fabsf(x));
    return fmaxf(x, 0.0f) + __logf(1.0f + e);
}

// truncation split: hi = trunc_bf16(x) (exact top-16), lo = trunc_bf16(x - hi).
__device__ __forceinline__ void tsplit(float x, short& hs, short& ls) {
    unsigned uh = __float_as_uint(x) & 0xFFFF0000u;
    float r = x - __uint_as_float(uh);
    hs = (short)(uh >> 16);
    ls = (short)(__float_as_uint(r) >> 16);
}

// ---- layer-1 merged A-fragment (k-packed hi/lo/bias, one MFMA per tile) ----
//  k0..k7  (G=0): wa_h wb_h b_h wa_h wb_h wa_h wb_h wa_l
//  k8..k11 (G=1): wb_l wa_l wb_l b_l
__device__ __forceinline__ void build_l1(const float* __restrict__ W,
                                         const float* __restrict__ Bv,
                                         int Mreal, int t, int lane, bf16x8& A) {
    int row = t * 16 + (lane & 15);
    int G = lane >> 4;
    float wa = 0.f, wb = 0.f, bi = 0.f;
    if (row < Mreal) { wa = W[2 * row]; wb = W[2 * row + 1]; bi = Bv[row]; }
    short wah, wal, wbh, wbl, bih, bil;
    tsplit(wa, wah, wal);
    tsplit(wb, wbh, wbl);
    tsplit(bi, bih, bil);
    #pragma unroll
    for (int j = 0; j < 8; ++j) A[j] = 0;
    if (G == 0) {
        A[0] = wah; A[1] = wbh; A[2] = bih; A[3] = wah;
        A[4] = wbh; A[5] = wah; A[6] = wbh; A[7] = wal;
    } else if (G == 1) {
        A[0] = wbl; A[1] = wal; A[2] = wbl; A[3] = bil;
    }
}

// ---- layer-2 A-fragment split, row-major W[M][K] ----
__device__ __forceinline__ void build_frag(const float* __restrict__ W,
                                           int Mreal, int Kreal, int Ks,
                                           int t, int u, int lane,
                                           bf16x8& hi, bf16x8& lo) {
    int row = t * 16 + (lane & 15);
    int kb = u * 32 + (lane >> 4) * 8;
    #pragma unroll
    for (int j = 0; j < 8; ++j) {
        int k = kb + j;
        float w = (row < Mreal && k < Kreal) ? W[row * Ks + k] : 0.0f;
        short hs, ls;
        tsplit(w, hs, ls);
        hi[j] = hs; lo[j] = ls;
    }
}

// tanh + trunc-split + LDS store
__device__ __forceinline__ void act_store_tanh(const f32x4* d,
                                               unsigned* ldsH, unsigned* ldsL,
                                               int cb, int G) {
    #pragma unroll
    for (int t = 0; t < 4; ++t) {
        float a0 = fast_tanh(d[t][0]);
        float a1 = fast_tanh(d[t][1]);
        float a2 = fast_tanh(d[t][2]);
        float a3 = fast_tanh(d[t][3]);
        unsigned u0 = __float_as_uint(a0), u1 = __float_as_uint(a1);
        unsigned u2 = __float_as_uint(a2), u3 = __float_as_uint(a3);
        unsigned h01 = __builtin_amdgcn_perm(u1, u0, PSEL);
        unsigned h23 = __builtin_amdgcn_perm(u3, u2, PSEL);
        float r0 = a0 - __uint_as_float(u0 & 0xFFFF0000u);
        float r1 = a1 - __uint_as_float(u1 & 0xFFFF0000u);
        float r2 = a2 - __uint_as_float(u2 & 0xFFFF0000u);
        float r3 = a3 - __uint_as_float(u3 & 0xFFFF0000u);
        unsigned l01 = __builtin_amdgcn_perm(__float_as_uint(r1), __float_as_uint(r0), PSEL);
        unsigned l23 = __builtin_amdgcn_perm(__float_as_uint(r3), __float_as_uint(r2), PSEL);
        int wo = cb + 8 * t + 2 * G;
        *reinterpret_cast<u32x2*>(&ldsH[wo]) = (u32x2){h01, h23};
        *reinterpret_cast<u32x2*>(&ldsL[wo]) = (u32x2){l01, l23};
    }
}

__global__ void __launch_bounds__(256)
__attribute__((amdgpu_waves_per_eu(2, 2)))
node_kernel(const float* __restrict__ y0,
            const float* __restrict__ tt,
            const float* __restrict__ fw1, const float* __restrict__ fb1,
            const float* __restrict__ fw2, const float* __restrict__ fb2,
            const float* __restrict__ fw3, const float* __restrict__ fb3,
            const float* __restrict__ gw1, const float* __restrict__ gb1,
            const float* __restrict__ gw2, const float* __restrict__ gb2,
            const float* __restrict__ gw3, const float* __restrict__ gb3,
            float* __restrict__ out)
{
    __shared__ __align__(16) unsigned lds_fhi[4][16 * STRIDE];
    __shared__ __align__(16) unsigned lds_flo[4][16 * STRIDE];
    __shared__ __align__(16) unsigned lds_ghi[4][16 * STRIDE];
    __shared__ __align__(16) unsigned lds_glo[4][16 * STRIDE];
    __shared__ float lds_y[4][2][16][2];
    __shared__ __align__(16) float lds_b2f[64];
    __shared__ __align__(16) float lds_b2g[64];
    __shared__ __align__(16) float lds_w3[4][64];          // f0,f1,g0,g1 rows
    __shared__ __align__(16) unsigned lds_w2lo[2][8][64 * 4]; // lo frags, lane-indexed

    const int lane  = threadIdx.x & 63;
    const int wIdx  = threadIdx.x >> 6;
    const int waveG = blockIdx.x * 4 + wIdx;
    const int c     = lane & 15;
    const int G     = lane >> 4;
    const bool lo16 = (lane < 16);
    const int cb    = c * STRIDE;
    const int lane4 = lane * 4;

    // block-shared tables
    if (threadIdx.x < 64) {
        int i = threadIdx.x;
        lds_b2f[i] = fb2[i];
        lds_b2g[i] = (i < 52) ? gb2[i] : 0.0f;
        lds_w3[0][i] = fw3[i];
        lds_w3[1][i] = fw3[64 + i];
        lds_w3[2][i] = (i < 52) ? gw3[i] : 0.0f;
        lds_w3[3][i] = (i < 52) ? gw3[52 + i] : 0.0f;
    }

    // ---- persistent weight fragments: hi in regs, lo in LDS (shared) ----
    bf16x8 fA1[4], gA1[4];
    bf16x8 fw2h[4][2], gw2h[4][2];
    #pragma unroll
    for (int t = 0; t < 4; ++t) {
        build_l1(fw1, fb1, 64, t, lane, fA1[t]);
        build_l1(gw1, gb1, 52, t, lane, gA1[t]);
        #pragma unroll
        for (int u = 0; u < 2; ++u) {
            bf16x8 lo;
            build_frag(fw2, 64, 64, 64, t, u, lane, fw2h[t][u], lo);
            if (wIdx == 0)
                *reinterpret_cast<bf16x8*>(&lds_w2lo[0][2 * t + u][lane4]) = lo;
            build_frag(gw2, 52, 52, 52, t, u, lane, gw2h[t][u], lo);
            if (wIdx == 0)
                *reinterpret_cast<bf16x8*>(&lds_w2lo[1][2 * t + u][lane4]) = lo;
        }
    }
    __syncthreads();

    const float dt = tt[1] - tt[0];
    const float b3a = fb3[0] + gb3[0];
    const float b3b = fb3[1] + gb3[1];
    const f32x4 zero4 = {0.f, 0.f, 0.f, 0.f};

    // ---- y0 init ----
    #pragma unroll 1
    for (int ct = 0; ct < 2; ++ct) {
        int sample = waveG * 32 + ct * 16 + c;
        if (lo16) {
            float2 yv = reinterpret_cast<const float2*>(y0)[sample];
            lds_y[wIdx][ct][c][0] = yv.x;
            lds_y[wIdx][ct][c][1] = yv.y;
            reinterpret_cast<float2*>(out)[sample] = yv;
        }
    }

    // ---- time loop ----
    #pragma unroll 1
    for (int s = 1; s < T; ++s) {
        #pragma unroll 1
        for (int ct = 0; ct < 2; ++ct) {
            float ya = lds_y[wIdx][ct][c][0];
            float yb = lds_y[wIdx][ct][c][1];

            // ---- y trunc 3-split -> k-packed B fragment ----
            unsigned ua = __float_as_uint(ya), ub = __float_as_uint(yb);
            unsigned uah = ua & 0xFFFF0000u;
            float ra = ya - __uint_as_float(uah);
            unsigned uam = __float_as_uint(ra) & 0xFFFF0000u;
            float ra2 = ra - __uint_as_float(uam);
            unsigned ubh = ub & 0xFFFF0000u;
            float rb = yb - __uint_as_float(ubh);
            unsigned ubm = __float_as_uint(rb) & 0xFFFF0000u;
            float rb2 = rb - __uint_as_float(ubm);

            unsigned w0g0 = __builtin_amdgcn_perm(ub, ua, PSEL);
            unsigned w1g0 = 0x00003F80u | uam;
            unsigned w2g0 = __builtin_amdgcn_perm(__float_as_uint(ra2), __float_as_uint(rb), PSEL);
            unsigned w3g0 = __builtin_amdgcn_perm(ua, __float_as_uint(rb2), PSEL);
            unsigned w0g1 = __builtin_amdgcn_perm(__float_as_uint(ra), ub, PSEL);
            unsigned w1g1 = (ubm >> 16) | 0x3F800000u;

            U4 yB;
            yB.u[0] = (G == 0) ? w0g0 : ((G == 1) ? w0g1 : 0u);
            yB.u[1] = (G == 0) ? w1g0 : ((G == 1) ? w1g1 : 0u);
            yB.u[2] = (G == 0) ? w2g0 : 0u;
            yB.u[3] = (G == 0) ? w3g0 : 0u;

            // ---- layer 1: one MFMA per tile ----
            f32x4 d1f[4], d1g[4];
            #pragma unroll
            for (int t = 0; t < 4; ++t) d1f[t] = MFMA(fA1[t], yB.v, zero4);
            act_store_tanh(d1f, lds_fhi[wIdx], lds_flo[wIdx], cb, G);
            #pragma unroll
            for (int t = 0; t < 4; ++t) d1g[t] = MFMA(gA1[t], yB.v, zero4);
            act_store_tanh(d1g, lds_ghi[wIdx], lds_glo[wIdx], cb, G);

            // ---- layer 2: 3 split passes; hi from regs, lo frags from LDS ----
            bf16x8 hH[2], hL[2];
            #pragma unroll
            for (int u = 0; u < 2; ++u) {
                int ro = cb + 16 * u + 4 * G;
                hH[u] = *reinterpret_cast<const bf16x8*>(&lds_fhi[wIdx][ro]);
                hL[u] = *reinterpret_cast<const bf16x8*>(&lds_flo[wIdx][ro]);
            }
            f32x4 d2f[4], d2g[4];
            #pragma unroll
            for (int t = 0; t < 4; ++t) {
                f32x4 a = *reinterpret_cast<const f32x4*>(&lds_b2f[16 * t + 4 * G]);
                #pragma unroll
                for (int u = 0; u < 2; ++u) {
                    bf16x8 wl = *reinterpret_cast<const bf16x8*>(&lds_w2lo[0][2 * t + u][lane4]);
                    a = MFMA(fw2h[t][u], hH[u], a);
                    a = MFMA(fw2h[t][u], hL[u], a);
                    a = MFMA(wl, hH[u], a);
                }
                d2f[t] = a;
            }
            #pragma unroll
            for (int u = 0; u < 2; ++u) {
                int ro = cb + 16 * u + 4 * G;
                hH[u] = *reinterpret_cast<const bf16x8*>(&lds_ghi[wIdx][ro]);
                hL[u] = *reinterpret_cast<const bf16x8*>(&lds_glo[wIdx][ro]);
            }
            #pragma unroll
            for (int t = 0; t < 4; ++t) {
                f32x4 a = *reinterpret_cast<const f32x4*>(&lds_b2g[16 * t + 4 * G]);
                #pragma unroll
                for (int u = 0; u < 2; ++u) {
                    bf16x8 wl = *reinterpret_cast<const bf16x8*>(&lds_w2lo[1][2 * t + u][lane4]);
                    a = MFMA(gw2h[t][u], hH[u], a);
                    a = MFMA(gw2h[t][u], hL[u], a);
                    a = MFMA(wl, hH[u], a);
                }
                d2g[t] = a;
            }

            // ---- layer 3 on VALU: softplus + f32 dots + butterfly reduce ----
            float pa = 0.f, pb = 0.f;
            #pragma unroll
            for (int t = 0; t < 4; ++t) {
                int fo = 16 * t + 4 * G;
                f32x4 wf0 = *reinterpret_cast<const f32x4*>(&lds_w3[0][fo]);
                f32x4 wf1 = *reinterpret_cast<const f32x4*>(&lds_w3[1][fo]);
                #pragma unroll
                for (int r = 0; r < 4; ++r) {
                    float sv = fast_sp(d2f[t][r]);
                    pa = fmaf(wf0[r], sv, pa);
                    pb = fmaf(wf1[r], sv, pb);
                }
                f32x4 wg0 = *reinterpret_cast<const f32x4*>(&lds_w3[2][fo]);
                f32x4 wg1 = *reinterpret_cast<const f32x4*>(&lds_w3[3][fo]);
                #pragma unroll
                for (int r = 0; r < 4; ++r) {
                    float sv = fast_sp(d2g[t][r]);
                    pa = fmaf(wg0[r], sv, pa);
                    pb = fmaf(wg1[r], sv, pb);
                }
            }
            pa += __shfl_xor(pa, 16); pa += __shfl_xor(pa, 32);
            pb += __shfl_xor(pb, 16); pb += __shfl_xor(pb, 32);

            // ---- Euler update + store ----
            if (lo16) {
                float nya = fmaf(pa + b3a, dt, ya);
                float nyb = fmaf(pb + b3b, dt, yb);
                lds_y[wIdx][ct][c][0] = nya;
                lds_y[wIdx][ct][c][1] = nyb;
                int sample = waveG * 32 + ct * 16 + c;
                reinterpret_cast<float2*>(out)[(size_t)s * BATCH + sample] =
                    make_float2(nya, nyb);
            }
        }
    }
}

extern "C" void kernel_launch(void* const* d_in, const int* in_sizes, int n_in,
                              void* d_out, int out_size, void* d_ws, size_t ws_size,
                              hipStream_t stream) {
    const float* y0  = (const float*)d_in[0];
    const float* tt  = (const float*)d_in[1];
    const float* fw1 = (const float*)d_in[2];
    const float* fb1 = (const float*)d_in[3];
    const float* fw2 = (const float*)d_in[4];
    const float* fb2 = (const float*)d_in[5];
    const float* fw3 = (const float*)d_in[6];
    const float* fb3 = (const float*)d_in[7];
    const float* gw1 = (const float*)d_in[8];
    const float* gb1 = (const float*)d_in[9];
    const float* gw2 = (const float*)d_in[10];
    const float* gb2 = (const float*)d_in[11];
    const float* gw3 = (const float*)d_in[12];
    const float* gb3 = (const float*)d_in[13];
    float* out = (float*)d_out;

    dim3 grid(512);    // 2048 waves, 32 samples/wave -> 2 blocks/CU, 2 waves/SIMD
    dim3 block(256);
    hipLaunchKernelGGL(node_kernel, grid, block, 0, stream,
                       y0, tt, fw1, fb1, fw2, fb2, fw3, fb3,
                       gw1, gb1, gw2, gb2, gw3, gb3, out);
}

// Round 7
// 4586.466 us; speedup vs baseline: 1.9384x; 1.8521x over previous
//
#include <hip/hip_runtime.h>

#define BATCH 65536
#define T 500
#define STRIDE 36   // words per sample region in act LDS (16B-aligned, R3-proven)

typedef __attribute__((ext_vector_type(8))) short bf16x8;
typedef __attribute__((ext_vector_type(4))) float f32x4;
typedef __attribute__((ext_vector_type(2))) unsigned u32x2;

#define MFMA(A, B, C) __builtin_amdgcn_mfma_f32_16x16x32_bf16(A, B, C, 0, 0, 0)
#define PSEL 0x07060302u   // v_perm: low16 = hi16(srcB), high16 = hi16(srcA)

union U4 { unsigned u[4]; bf16x8 v; };

__device__ __forceinline__ float fast_tanh(float x) {
    // tanh = 1 - 2*rcp(exp(2x)+1); raw v_rcp_f32 (~1ulp) avoids div expansion
    float e = __expf(2.0f * x);
    return 1.0f - 2.0f * __builtin_amdgcn_rcpf(e + 1.0f);
}
__device__ __forceinline__ float fast_sp(float x) {
    float e = __expf(-fabsf(x));
    return fmaxf(x, 0.0f) + __logf(1.0f + e);
}

// truncation split: hi = trunc_bf16(x) (exact top-16), lo = trunc_bf16(x - hi).
__device__ __forceinline__ void tsplit(float x, short& hs, short& ls) {
    unsigned uh = __float_as_uint(x) & 0xFFFF0000u;
    float r = x - __uint_as_float(uh);
    hs = (short)(uh >> 16);
    ls = (short)(__float_as_uint(r) >> 16);
}

// ---- layer-1 merged A-fragment (k-packed hi/lo/bias, one MFMA per tile) ----
//  k0..k7  (G=0): wa_h wb_h b_h wa_h wb_h wa_h wb_h wa_l
//  k8..k11 (G=1): wb_l wa_l wb_l b_l
__device__ __forceinline__ void build_l1(const float* __restrict__ W,
                                         const float* __restrict__ Bv,
                                         int Mreal, int t, int lane, bf16x8& A) {
    int row = t * 16 + (lane & 15);
    int G = lane >> 4;
    float wa = 0.f, wb = 0.f, bi = 0.f;
    if (row < Mreal) { wa = W[2 * row]; wb = W[2 * row + 1]; bi = Bv[row]; }
    short wah, wal, wbh, wbl, bih, bil;
    tsplit(wa, wah, wal);
    tsplit(wb, wbh, wbl);
    tsplit(bi, bih, bil);
    #pragma unroll
    for (int j = 0; j < 8; ++j) A[j] = 0;
    if (G == 0) {
        A[0] = wah; A[1] = wbh; A[2] = bih; A[3] = wah;
        A[4] = wbh; A[5] = wah; A[6] = wbh; A[7] = wal;
    } else if (G == 1) {
        A[0] = wbl; A[1] = wal; A[2] = wbl; A[3] = bil;
    }
}

// ---- layer-2 A-fragment split, row-major W[M][K] ----
__device__ __forceinline__ void build_frag(const float* __restrict__ W,
                                           int Mreal, int Kreal, int Ks,
                                           int t, int u, int lane,
                                           bf16x8& hi, bf16x8& lo) {
    int row = t * 16 + (lane & 15);
    int kb = u * 32 + (lane >> 4) * 8;
    #pragma unroll
    for (int j = 0; j < 8; ++j) {
        int k = kb + j;
        float w = (row < Mreal && k < Kreal) ? W[row * Ks + k] : 0.0f;
        short hs, ls;
        tsplit(w, hs, ls);
        hi[j] = hs; lo[j] = ls;
    }
}

// tanh + trunc-split + LDS store
__device__ __forceinline__ void act_store_tanh(const f32x4* d,
                                               unsigned* ldsH, unsigned* ldsL,
                                               int cb, int G) {
    #pragma unroll
    for (int t = 0; t < 4; ++t) {
        float a0 = fast_tanh(d[t][0]);
        float a1 = fast_tanh(d[t][1]);
        float a2 = fast_tanh(d[t][2]);
        float a3 = fast_tanh(d[t][3]);
        unsigned u0 = __float_as_uint(a0), u1 = __float_as_uint(a1);
        unsigned u2 = __float_as_uint(a2), u3 = __float_as_uint(a3);
        unsigned h01 = __builtin_amdgcn_perm(u1, u0, PSEL);
        unsigned h23 = __builtin_amdgcn_perm(u3, u2, PSEL);
        float r0 = a0 - __uint_as_float(u0 & 0xFFFF0000u);
        float r1 = a1 - __uint_as_float(u1 & 0xFFFF0000u);
        float r2 = a2 - __uint_as_float(u2 & 0xFFFF0000u);
        float r3 = a3 - __uint_as_float(u3 & 0xFFFF0000u);
        unsigned l01 = __builtin_amdgcn_perm(__float_as_uint(r1), __float_as_uint(r0), PSEL);
        unsigned l23 = __builtin_amdgcn_perm(__float_as_uint(r3), __float_as_uint(r2), PSEL);
        int wo = cb + 8 * t + 2 * G;
        *reinterpret_cast<u32x2*>(&ldsH[wo]) = (u32x2){h01, h23};
        *reinterpret_cast<u32x2*>(&ldsL[wo]) = (u32x2){l01, l23};
    }
}

__global__ void __launch_bounds__(256)
__attribute__((amdgpu_waves_per_eu(2, 2)))
node_kernel(const float* __restrict__ y0,
            const float* __restrict__ tt,
            const float* __restrict__ fw1, const float* __restrict__ fb1,
            const float* __restrict__ fw2, const float* __restrict__ fb2,
            const float* __restrict__ fw3, const float* __restrict__ fb3,
            const float* __restrict__ gw1, const float* __restrict__ gb1,
            const float* __restrict__ gw2, const float* __restrict__ gb2,
            const float* __restrict__ gw3, const float* __restrict__ gb3,
            float* __restrict__ out)
{
    // act buffers (per wave) + all weight fragments (shared per block)
    __shared__ __align__(16) unsigned lds_fhi[4][16 * STRIDE];
    __shared__ __align__(16) unsigned lds_flo[4][16 * STRIDE];
    __shared__ __align__(16) unsigned lds_ghi[4][16 * STRIDE];
    __shared__ __align__(16) unsigned lds_glo[4][16 * STRIDE];
    __shared__ float lds_y[4][2][16][2];
    __shared__ __align__(16) float lds_b2[2][64];            // f,g layer-2 bias
    __shared__ __align__(16) float lds_w3[4][64];            // f0,f1,g0,g1 rows
    __shared__ __align__(16) unsigned lds_l1[2][4][64 * 4];  // merged L1 frags
    __shared__ __align__(16) unsigned lds_w2h[2][8][64 * 4]; // L2 hi frags
    __shared__ __align__(16) unsigned lds_w2l[2][8][64 * 4]; // L2 lo frags
    // total approx 80 KB -> 2 blocks/CU

    const int lane  = threadIdx.x & 63;
    const int wIdx  = threadIdx.x >> 6;
    const int waveG = blockIdx.x * 4 + wIdx;
    const int c     = lane & 15;
    const int G     = lane >> 4;
    const bool lo16 = (lane < 16);
    const int cb    = c * STRIDE;
    const int lane4 = lane * 4;

    // block-shared tables
    if (threadIdx.x < 64) {
        int i = threadIdx.x;
        lds_b2[0][i] = fb2[i];
        lds_b2[1][i] = (i < 52) ? gb2[i] : 0.0f;
        lds_w3[0][i] = fw3[i];
        lds_w3[1][i] = fw3[64 + i];
        lds_w3[2][i] = (i < 52) ? gw3[i] : 0.0f;
        lds_w3[3][i] = (i < 52) ? gw3[52 + i] : 0.0f;
    }

    // ---- build all weight fragments into LDS (wave wIdx builds tile wIdx) ----
    {
        const int t = wIdx;
        bf16x8 A, hi, lo;
        build_l1(fw1, fb1, 64, t, lane, A);
        *reinterpret_cast<bf16x8*>(&lds_l1[0][t][lane4]) = A;
        build_l1(gw1, gb1, 52, t, lane, A);
        *reinterpret_cast<bf16x8*>(&lds_l1[1][t][lane4]) = A;
        #pragma unroll
        for (int u = 0; u < 2; ++u) {
            build_frag(fw2, 64, 64, 64, t, u, lane, hi, lo);
            *reinterpret_cast<bf16x8*>(&lds_w2h[0][2 * t + u][lane4]) = hi;
            *reinterpret_cast<bf16x8*>(&lds_w2l[0][2 * t + u][lane4]) = lo;
            build_frag(gw2, 52, 52, 52, t, u, lane, hi, lo);
            *reinterpret_cast<bf16x8*>(&lds_w2h[1][2 * t + u][lane4]) = hi;
            *reinterpret_cast<bf16x8*>(&lds_w2l[1][2 * t + u][lane4]) = lo;
        }
    }
    __syncthreads();

    const float dt = tt[1] - tt[0];
    const float b3a = fb3[0] + gb3[0];
    const float b3b = fb3[1] + gb3[1];
    const f32x4 zero4 = {0.f, 0.f, 0.f, 0.f};

    // ---- y0 init ----
    #pragma unroll 1
    for (int ct = 0; ct < 2; ++ct) {
        int sample = waveG * 32 + ct * 16 + c;
        if (lo16) {
            float2 yv = reinterpret_cast<const float2*>(y0)[sample];
            lds_y[wIdx][ct][c][0] = yv.x;
            lds_y[wIdx][ct][c][1] = yv.y;
            reinterpret_cast<float2*>(out)[sample] = yv;
        }
    }

    // ---- time loop ----
    #pragma unroll 1
    for (int s = 1; s < T; ++s) {
        #pragma unroll 1
        for (int ct = 0; ct < 2; ++ct) {
            // opaque zero index, redefined per iteration: blocks LICM/CSE from
            // hoisting weight-fragment loads into (spilled) registers, while
            // keeping LDS addrspace and (<<2 => 16B) alignment provable.
            unsigned zoff = 0;
            asm volatile("" : "+v"(zoff));
            const unsigned z4 = zoff << 2;

            float ya = lds_y[wIdx][ct][c][0];
            float yb = lds_y[wIdx][ct][c][1];

            // ---- y trunc 3-split -> k-packed B fragment ----
            unsigned ua = __float_as_uint(ya), ub = __float_as_uint(yb);
            unsigned uah = ua & 0xFFFF0000u;
            float ra = ya - __uint_as_float(uah);
            unsigned uam = __float_as_uint(ra) & 0xFFFF0000u;
            float ra2 = ra - __uint_as_float(uam);
            unsigned ubh = ub & 0xFFFF0000u;
            float rb = yb - __uint_as_float(ubh);
            unsigned ubm = __float_as_uint(rb) & 0xFFFF0000u;
            float rb2 = rb - __uint_as_float(ubm);

            unsigned w0g0 = __builtin_amdgcn_perm(ub, ua, PSEL);
            unsigned w1g0 = 0x00003F80u | uam;
            unsigned w2g0 = __builtin_amdgcn_perm(__float_as_uint(ra2), __float_as_uint(rb), PSEL);
            unsigned w3g0 = __builtin_amdgcn_perm(ua, __float_as_uint(rb2), PSEL);
            unsigned w0g1 = __builtin_amdgcn_perm(__float_as_uint(ra), ub, PSEL);
            unsigned w1g1 = (ubm >> 16) | 0x3F800000u;

            U4 yB;
            yB.u[0] = (G == 0) ? w0g0 : ((G == 1) ? w0g1 : 0u);
            yB.u[1] = (G == 0) ? w1g0 : ((G == 1) ? w1g1 : 0u);
            yB.u[2] = (G == 0) ? w2g0 : 0u;
            yB.u[3] = (G == 0) ? w3g0 : 0u;

            // ---- layer 1: one MFMA per tile, A frags from LDS ----
            f32x4 d1f[4], d1g[4];
            #pragma unroll
            for (int t = 0; t < 4; ++t) {
                bf16x8 A = *reinterpret_cast<const bf16x8*>(&lds_l1[0][t][lane4 + z4]);
                d1f[t] = MFMA(A, yB.v, zero4);
            }
            act_store_tanh(d1f, lds_fhi[wIdx], lds_flo[wIdx], cb, G);
            #pragma unroll
            for (int t = 0; t < 4; ++t) {
                bf16x8 A = *reinterpret_cast<const bf16x8*>(&lds_l1[1][t][lane4 + z4]);
                d1g[t] = MFMA(A, yB.v, zero4);
            }
            act_store_tanh(d1g, lds_ghi[wIdx], lds_glo[wIdx], cb, G);

            // ---- layer 2: 3 split passes; all weight frags from LDS ----
            bf16x8 hH[2], hL[2];
            #pragma unroll
            for (int u = 0; u < 2; ++u) {
                int ro = cb + 16 * u + 4 * G;
                hH[u] = *reinterpret_cast<const bf16x8*>(&lds_fhi[wIdx][ro]);
                hL[u] = *reinterpret_cast<const bf16x8*>(&lds_flo[wIdx][ro]);
            }
            f32x4 d2f[4], d2g[4];
            #pragma unroll
            for (int t = 0; t < 4; ++t) {
                f32x4 a = *reinterpret_cast<const f32x4*>(&lds_b2[0][16 * t + 4 * G + z4]);
                #pragma unroll
                for (int u = 0; u < 2; ++u) {
                    bf16x8 wh = *reinterpret_cast<const bf16x8*>(&lds_w2h[0][2 * t + u][lane4 + z4]);
                    bf16x8 wl = *reinterpret_cast<const bf16x8*>(&lds_w2l[0][2 * t + u][lane4 + z4]);
                    a = MFMA(wh, hH[u], a);
                    a = MFMA(wh, hL[u], a);
                    a = MFMA(wl, hH[u], a);
                }
                d2f[t] = a;
            }
            #pragma unroll
            for (int u = 0; u < 2; ++u) {
                int ro = cb + 16 * u + 4 * G;
                hH[u] = *reinterpret_cast<const bf16x8*>(&lds_ghi[wIdx][ro]);
                hL[u] = *reinterpret_cast<const bf16x8*>(&lds_glo[wIdx][ro]);
            }
            #pragma unroll
            for (int t = 0; t < 4; ++t) {
                f32x4 a = *reinterpret_cast<const f32x4*>(&lds_b2[1][16 * t + 4 * G + z4]);
                #pragma unroll
                for (int u = 0; u < 2; ++u) {
                    bf16x8 wh = *reinterpret_cast<const bf16x8*>(&lds_w2h[1][2 * t + u][lane4 + z4]);
                    bf16x8 wl = *reinterpret_cast<const bf16x8*>(&lds_w2l[1][2 * t + u][lane4 + z4]);
                    a = MFMA(wh, hH[u], a);
                    a = MFMA(wh, hL[u], a);
                    a = MFMA(wl, hH[u], a);
                }
                d2g[t] = a;
            }

            // ---- layer 3 on VALU: softplus + f32 dots + butterfly reduce ----
            float pa = 0.f, pb = 0.f;
            #pragma unroll
            for (int t = 0; t < 4; ++t) {
                int fo = 16 * t + 4 * G + z4;
                f32x4 wf0 = *reinterpret_cast<const f32x4*>(&lds_w3[0][fo]);
                f32x4 wf1 = *reinterpret_cast<const f32x4*>(&lds_w3[1][fo]);
                #pragma unroll
                for (int r = 0; r < 4; ++r) {
                    float sv = fast_sp(d2f[t][r]);
                    pa = fmaf(wf0[r], sv, pa);
                    pb = fmaf(wf1[r], sv, pb);
                }
                f32x4 wg0 = *reinterpret_cast<const f32x4*>(&lds_w3[2][fo]);
                f32x4 wg1 = *reinterpret_cast<const f32x4*>(&lds_w3[3][fo]);
                #pragma unroll
                for (int r = 0; r < 4; ++r) {
                    float sv = fast_sp(d2g[t][r]);
                    pa = fmaf(wg0[r], sv, pa);
                    pb = fmaf(wg1[r], sv, pb);
                }
            }
            pa += __shfl_xor(pa, 16); pa += __shfl_xor(pa, 32);
            pb += __shfl_xor(pb, 16); pb += __shfl_xor(pb, 32);

            // ---- Euler update + store ----
            if (lo16) {
                float nya = fmaf(pa + b3a, dt, ya);
                float nyb = fmaf(pb + b3b, dt, yb);
                lds_y[wIdx][ct][c][0] = nya;
                lds_y[wIdx][ct][c][1] = nyb;
                int sample = waveG * 32 + ct * 16 + c;
                reinterpret_cast<float2*>(out)[(size_t)s * BATCH + sample] =
                    make_float2(nya, nyb);
            }
        }
    }
}

extern "C" void kernel_launch(void* const* d_in, const int* in_sizes, int n_in,
                              void* d_out, int out_size, void* d_ws, size_t ws_size,
                              hipStream_t stream) {
    const float* y0  = (const float*)d_in[0];
    const float* tt  = (const float*)d_in[1];
    const float* fw1 = (const float*)d_in[2];
    const float* fb1 = (const float*)d_in[3];
    const float* fw2 = (const float*)d_in[4];
    const float* fb2 = (const float*)d_in[5];
    const float* fw3 = (const float*)d_in[6];
    const float* fb3 = (const float*)d_in[7];
    const float* gw1 = (const float*)d_in[8];
    const float* gb1 = (const float*)d_in[9];
    const float* gw2 = (const float*)d_in[10];
    const float* gb2 = (const float*)d_in[11];
    const float* gw3 = (const float*)d_in[12];
    const float* gb3 = (const float*)d_in[13];
    float* out = (float*)d_out;

    dim3 grid(512);    // 2048 waves, 32 samples/wave -> 2 blocks/CU, 2 waves/SIMD
    dim3 block(256);
    hipLaunchKernelGGL(node_kernel, grid, block, 0, stream,
                       y0, tt, fw1, fb1, fw2, fb2, fw3, fb3,
                       gw1, gb1, gw2, gb2, gw3, gb3, out);
}